// Round 1
// baseline (1207.417 us; speedup 1.0000x reference)
//
#include <hip/hip_runtime.h>
#include <cmath>

#define BB 4
#define NN 4096
#define DD 244
#define FS 68   // padded feature dim (66 used: charge, 64 shell, sqrt(mass))
#define LS 72   // LDS row stride in floats (16B aligned, conflict-friendly)
#define ROWS 32 // query rows per block
#define MT 128  // m-tile for rowstats
#define MT2 64  // m-tile for pv

// qreg weight: energy = 1*c_n c_m + 0.5*shell.shell + 0.1*sqrt(mn)sqrt(mm) + 0.3|n-m|
// store q = -w_j * feat_j so score s = dot(q, k) - 0.3|n-m| = -energy
__device__ __forceinline__ float neg_qw(int j) {
    if (j == 0) return -1.0f;
    if (j < 65) return -0.5f;
    if (j == 65) return -0.1f;
    return 0.0f;
}

__global__ __launch_bounds__(64) void feat_kernel(const float* __restrict__ charge,
                                                  const float* __restrict__ shell,
                                                  const float* __restrict__ mass,
                                                  float* __restrict__ feat) {
    int row = blockIdx.x;      // 0..B*N-1
    int t = threadIdx.x;       // 0..63
    feat[(size_t)row * FS + 1 + t] = shell[(size_t)row * 64 + t];
    if (t == 0) {
        feat[(size_t)row * FS + 0]  = charge[row];
        feat[(size_t)row * FS + 65] = sqrtf(mass[row]);
        feat[(size_t)row * FS + 66] = 0.0f;
        feat[(size_t)row * FS + 67] = 0.0f;
    }
}

// C[r][c] = sum_k A[r][k] * Bm[c][k] + bias[c]   (A: [R x 244], Bm: [244 x 244])
__global__ __launch_bounds__(256) void gemm_nt_bias(const float* __restrict__ A,
                                                    const float* __restrict__ Bm,
                                                    const float* __restrict__ bias,
                                                    float* __restrict__ C) {
    __shared__ __align__(16) float sA[16][68];
    __shared__ __align__(16) float sB[16][68];
    int t = threadIdx.x;
    int tx = t & 15, ty = t >> 4;
    int rb = blockIdx.x * 64, cb = blockIdx.y * 64;
    float acc[4][4] = {};
    int lrow = t >> 2;            // 0..63
    int lk = (t & 3) * 4;         // 0,4,8,12
    for (int k0 = 0; k0 < DD; k0 += 16) {
        __syncthreads();
        int gk = k0 + lk;
        float4 av = make_float4(0, 0, 0, 0), bv4 = make_float4(0, 0, 0, 0);
        if (gk < DD) {
            av = *(const float4*)(A + (size_t)(rb + lrow) * DD + gk);
            int col = cb + lrow;
            if (col < DD) bv4 = *(const float4*)(Bm + (size_t)col * DD + gk);
        }
        sA[lk + 0][lrow] = av.x; sA[lk + 1][lrow] = av.y;
        sA[lk + 2][lrow] = av.z; sA[lk + 3][lrow] = av.w;
        sB[lk + 0][lrow] = bv4.x; sB[lk + 1][lrow] = bv4.y;
        sB[lk + 2][lrow] = bv4.z; sB[lk + 3][lrow] = bv4.w;
        __syncthreads();
#pragma unroll
        for (int k = 0; k < 16; ++k) {
            float4 a4 = *(const float4*)&sA[k][ty * 4];
            float4 b4 = *(const float4*)&sB[k][tx * 4];
            float ar[4] = {a4.x, a4.y, a4.z, a4.w};
            float br[4] = {b4.x, b4.y, b4.z, b4.w};
#pragma unroll
            for (int i = 0; i < 4; ++i)
#pragma unroll
                for (int j = 0; j < 4; ++j) acc[i][j] += ar[i] * br[j];
        }
    }
#pragma unroll
    for (int i = 0; i < 4; ++i) {
        int rr = rb + ty * 4 + i;
#pragma unroll
        for (int j = 0; j < 4; ++j) {
            int cc = cb + tx * 4 + j;
            if (cc < DD) C[(size_t)rr * DD + cc] = acc[i][j] + bias[cc];
        }
    }
}

// Per row: M = max_m s, F = sum_all exp(s-M), S = sum_{m<=n} exp(s-M)
// alpha = scale / (scale*S + 1e-8*F), scale = min(val/(1+1e-6), 1)
__global__ __launch_bounds__(256) void rowstats_kernel(const float* __restrict__ feat,
                                                       const float* __restrict__ valence,
                                                       float* __restrict__ rowstats) {
    __shared__ __align__(16) float sK[MT * LS];
    __shared__ float red[ROWS][8][3];
    int n0 = blockIdx.x * ROWS;
    int b = blockIdx.y;
    const float* featB = feat + (size_t)b * NN * FS;
    int t = threadIdx.x;
    int r = t >> 3, g = t & 7;
    int n = n0 + r;
    // load my q row into registers (negated+scaled)
    float q[FS];
    {
        const float4* qp4 = (const float4*)(featB + (size_t)n * FS);
#pragma unroll
        for (int jj = 0; jj < FS / 4; ++jj) {
            float4 v = qp4[jj];
            q[4 * jj + 0] = neg_qw(4 * jj + 0) * v.x;
            q[4 * jj + 1] = neg_qw(4 * jj + 1) * v.y;
            q[4 * jj + 2] = neg_qw(4 * jj + 2) * v.z;
            q[4 * jj + 3] = neg_qw(4 * jj + 3) * v.w;
        }
    }
    float M = -INFINITY, F = 0.0f, S = 0.0f;
    for (int m0 = 0; m0 < NN; m0 += MT) {
        __syncthreads();
        for (int qq = t; qq < MT * FS; qq += 256) {
            int mr = qq / FS, j = qq % FS;
            sK[mr * LS + j] = featB[(size_t)(m0 + mr) * FS + j];
        }
        __syncthreads();
        for (int i = 0; i < MT / 8; ++i) {
            int mm = g + 8 * i;
            int m = m0 + mm;
            const float4* kp4 = (const float4*)&sK[mm * LS];
            float dot = 0.0f;
#pragma unroll
            for (int jj = 0; jj < FS / 4; ++jj) {
                float4 kv = kp4[jj];
                dot += q[4 * jj + 0] * kv.x + q[4 * jj + 1] * kv.y +
                       q[4 * jj + 2] * kv.z + q[4 * jj + 3] * kv.w;
            }
            float s = dot - 0.3f * fabsf((float)(n - m));
            if (s > M) {
                float c = __expf(M - s);
                F *= c; S *= c; M = s;
            }
            float e = __expf(s - M);
            F += e;
            if (m <= n) S += e;
        }
    }
    red[r][g][0] = M; red[r][g][1] = F; red[r][g][2] = S;
    __syncthreads();
    if (g == 0) {
        float Mm = M;
#pragma unroll
        for (int k = 1; k < 8; ++k) Mm = fmaxf(Mm, red[r][k][0]);
        float Ff = 0.0f, Ss = 0.0f;
#pragma unroll
        for (int k = 0; k < 8; ++k) {
            float c = __expf(red[r][k][0] - Mm);
            Ff += red[r][k][1] * c;
            Ss += red[r][k][2] * c;
        }
        float val = valence[(size_t)b * NN + n];
        float scale = fminf(val / (1.0f + 1e-6f), 1.0f);
        float alpha = scale / (scale * Ss + 1e-8f * Ff);
        rowstats[((size_t)b * NN + n) * 2 + 0] = Mm;
        rowstats[((size_t)b * NN + n) * 2 + 1] = alpha;
    }
}

// O[n][:] = alpha * sum_{m<=n} exp(s-M) * V[m][:]
__global__ __launch_bounds__(256) void pv_kernel(const float* __restrict__ feat,
                                                 const float* __restrict__ V,
                                                 const float* __restrict__ rowstats,
                                                 float* __restrict__ O) {
    __shared__ __align__(16) float sK[MT2 * LS];
    __shared__ float sW[ROWS][MT2 + 1];
    int n0 = blockIdx.x * ROWS;
    int b = blockIdx.y;
    const float* featB = feat + (size_t)b * NN * FS;
    int t = threadIdx.x;
    int rw = t & 31, g = t >> 5;     // rw: row 0..31, g: 0..7 (d-group)
    int n = n0 + rw;
    float M = rowstats[((size_t)b * NN + n) * 2 + 0];
    float alpha = rowstats[((size_t)b * NN + n) * 2 + 1];
    float q[FS];
    {
        const float4* qp4 = (const float4*)(featB + (size_t)n * FS);
#pragma unroll
        for (int jj = 0; jj < FS / 4; ++jj) {
            float4 v = qp4[jj];
            q[4 * jj + 0] = neg_qw(4 * jj + 0) * v.x;
            q[4 * jj + 1] = neg_qw(4 * jj + 1) * v.y;
            q[4 * jj + 2] = neg_qw(4 * jj + 2) * v.z;
            q[4 * jj + 3] = neg_qw(4 * jj + 3) * v.w;
        }
    }
    float acc[32];
#pragma unroll
    for (int j = 0; j < 32; ++j) acc[j] = 0.0f;
    int d0 = g * 32;
    int lastt = (n0 + ROWS - 1) / MT2;
    for (int mt = 0; mt <= lastt; ++mt) {
        int m0 = mt * MT2;
        __syncthreads();
        for (int qq = t; qq < MT2 * FS; qq += 256) {
            int mr = qq / FS, j = qq % FS;
            sK[mr * LS + j] = featB[(size_t)(m0 + mr) * FS + j];
        }
        __syncthreads();
#pragma unroll
        for (int i = 0; i < 8; ++i) {
            int mm = g + 8 * i;
            int m = m0 + mm;
            const float4* kp4 = (const float4*)&sK[mm * LS];
            float dot = 0.0f;
#pragma unroll
            for (int jj = 0; jj < FS / 4; ++jj) {
                float4 kv = kp4[jj];
                dot += q[4 * jj + 0] * kv.x + q[4 * jj + 1] * kv.y +
                       q[4 * jj + 2] * kv.z + q[4 * jj + 3] * kv.w;
            }
            float s = dot - 0.3f * fabsf((float)(n - m));
            sW[rw][mm] = (m <= n) ? __expf(s - M) : 0.0f;
        }
        __syncthreads();
        for (int mm = 0; mm < MT2; ++mm) {
            float wgt = sW[rw][mm];
            if (wgt != 0.0f) {
                const float* vp = V + ((size_t)b * NN + m0 + mm) * DD + d0;
#pragma unroll
                for (int j = 0; j < 8; ++j) {
                    float4 v = *(const float4*)(vp + 4 * j);
                    acc[4 * j + 0] += wgt * v.x;
                    acc[4 * j + 1] += wgt * v.y;
                    acc[4 * j + 2] += wgt * v.z;
                    acc[4 * j + 3] += wgt * v.w;
                }
            }
        }
    }
    float* op = O + ((size_t)b * NN + n) * DD + d0;
#pragma unroll
    for (int j = 0; j < 32; ++j)
        if (d0 + j < DD) op[j] = alpha * acc[j];
}

extern "C" void kernel_launch(void* const* d_in, const int* in_sizes, int n_in,
                              void* d_out, int out_size, void* d_ws, size_t ws_size,
                              hipStream_t stream) {
    (void)in_sizes; (void)n_in; (void)out_size; (void)ws_size;
    const float* charge  = (const float*)d_in[0];
    const float* shell   = (const float*)d_in[1];
    const float* mass    = (const float*)d_in[2];
    const float* valence = (const float*)d_in[3];
    // d_in[4] = position (== arange, use indices directly)
    const float* x  = (const float*)d_in[5];
    const float* Wv = (const float*)d_in[6];
    const float* bv = (const float*)d_in[7];
    const float* Wo = (const float*)d_in[8];
    const float* bo = (const float*)d_in[9];
    float* out = (float*)d_out;
    float* ws = (float*)d_ws;
    const size_t BN = (size_t)BB * NN;

    float* feat     = ws;                    // BN*FS
    float* V        = feat + BN * FS;        // BN*DD
    float* O        = V + BN * DD;           // BN*DD
    float* rowstats = O + BN * DD;           // BN*2

    feat_kernel<<<BB * NN, 64, 0, stream>>>(charge, shell, mass, feat);
    gemm_nt_bias<<<dim3((BB * NN) / 64, (DD + 63) / 64), 256, 0, stream>>>(x, Wv, bv, V);
    rowstats_kernel<<<dim3(NN / ROWS, BB), 256, 0, stream>>>(feat, valence, rowstats);
    pv_kernel<<<dim3(NN / ROWS, BB), 256, 0, stream>>>(feat, V, rowstats, O);
    gemm_nt_bias<<<dim3((BB * NN) / 64, (DD + 63) / 64), 256, 0, stream>>>(O, Wo, bo, out);
}

// Round 3
// 586.685 us; speedup vs baseline: 2.0580x; 2.0580x over previous
//
#include <hip/hip_runtime.h>
#include <cmath>

#define BB 4
#define NN 4096
#define DD 244
#define DP 256
#define FSP 96
#define KC 3   // FSP/32 k-chunks for scores

typedef _Float16 half8 __attribute__((ext_vector_type(8)));
typedef float float4v __attribute__((ext_vector_type(4)));
typedef unsigned int uint;

#define MFMA16 __builtin_amdgcn_mfma_f32_16x16x32_f16

static __device__ __forceinline__ uint pack2(float a, float b) {
    _Float16 ha = (_Float16)a, hb = (_Float16)b;
    unsigned short ua = __builtin_bit_cast(unsigned short, ha);
    unsigned short ub = __builtin_bit_cast(unsigned short, hb);
    return (uint)ua | ((uint)ub << 16);
}

// ---------------- prep kernels ----------------
__global__ __launch_bounds__(256) void prep_x(const float* __restrict__ x,
                                              _Float16* __restrict__ xh) {
    size_t i = blockIdx.x; int k = threadIdx.x;
    xh[i * DP + k] = (k < DD) ? (_Float16)x[i * DD + k] : (_Float16)0.f;
}

__global__ __launch_bounds__(256) void prep_w(const float* __restrict__ Wv,
                                              const float* __restrict__ Wo,
                                              _Float16* __restrict__ Wvh,
                                              _Float16* __restrict__ Woh) {
    int r = blockIdx.x, k = threadIdx.x;
    const float* src = blockIdx.y ? Wo : Wv;
    _Float16* dst = blockIdx.y ? Woh : Wvh;
    dst[(size_t)r * DP + k] =
        (r < DD && k < DD) ? (_Float16)src[(size_t)r * DD + k] : (_Float16)0.f;
}

// feature order: k 0..63 = shell, 64 = charge, 65 = sqrt(mass), 66..95 = 0
// Qb = -weight * feat  (so score = dot(Qb_n, Kb_m) - 0.3|n-m| = -energy)
__global__ __launch_bounds__(64) void prep_feat(const float* __restrict__ charge,
                                                const float* __restrict__ shell,
                                                const float* __restrict__ mass,
                                                _Float16* __restrict__ Qb,
                                                _Float16* __restrict__ Kb) {
    size_t row = blockIdx.x; int t = threadIdx.x;
    float v = shell[row * 64 + t];
    Kb[row * FSP + t] = (_Float16)v;
    Qb[row * FSP + t] = (_Float16)(-0.5f * v);
    int k2 = 64 + t;
    if (k2 < FSP) {
        float v2 = 0.f, q2 = 0.f;
        if (t == 0) { v2 = charge[row]; q2 = -1.0f * v2; }
        else if (t == 1) { v2 = sqrtf(mass[row]); q2 = -0.1f * v2; }
        Kb[row * FSP + k2] = (_Float16)v2;
        Qb[row * FSP + k2] = (_Float16)q2;
    }
}

// Vh [B*N][DP] f16 -> Vt [B][DP][N] f16
__global__ __launch_bounds__(256) void transpose_v(const _Float16* __restrict__ Vh,
                                                   _Float16* __restrict__ Vt) {
    __shared__ _Float16 tile[64][65];
    int n0 = blockIdx.x * 64, d0 = blockIdx.y * 64, b = blockIdx.z;
    int t = threadIdx.x;
#pragma unroll
    for (int i = 0; i < 16; ++i) {
        int idx = t + 256 * i;
        int r = idx >> 6, cc = idx & 63;
        tile[r][cc] = Vh[(size_t)(b * NN + n0 + r) * DP + d0 + cc];
    }
    __syncthreads();
#pragma unroll
    for (int i = 0; i < 16; ++i) {
        int idx = t + 256 * i;
        int dr = idx >> 6, nc = idx & 63;
        Vt[(size_t)b * DP * NN + (size_t)(d0 + dr) * NN + n0 + nc] = tile[nc][dr];
    }
}

// ---------------- f16 MFMA GEMM: C[r][c] = sum_k A[r][k]*W[c][k] + bias[c] ----------------
template <bool F16OUT>
__global__ __launch_bounds__(64) void gemm16(const _Float16* __restrict__ A,
                                             const _Float16* __restrict__ W,
                                             const float* __restrict__ bias,
                                             void* __restrict__ Cout) {
    int l = threadIdx.x, c = l & 15, g = l >> 4;
    int rb = blockIdx.x * 32, cb = blockIdx.y * 32;
    float4v acc[2][2];
#pragma unroll
    for (int i = 0; i < 2; ++i)
#pragma unroll
        for (int j = 0; j < 2; ++j) acc[i][j] = (float4v){0.f, 0.f, 0.f, 0.f};
#pragma unroll
    for (int kc = 0; kc < 8; ++kc) {
        half8 af[2], bf[2];
#pragma unroll
        for (int i = 0; i < 2; ++i) {
            af[i] = *(const half8*)(A + (size_t)(rb + 16 * i + c) * DP + kc * 32 + g * 8);
            bf[i] = *(const half8*)(W + (size_t)(cb + 16 * i + c) * DP + kc * 32 + g * 8);
        }
#pragma unroll
        for (int qg = 0; qg < 2; ++qg)
#pragma unroll
            for (int cg = 0; cg < 2; ++cg)
                acc[qg][cg] = MFMA16(af[qg], bf[cg], acc[qg][cg], 0, 0, 0);
    }
#pragma unroll
    for (int qg = 0; qg < 2; ++qg)
#pragma unroll
        for (int cg = 0; cg < 2; ++cg) {
            int col = cb + 16 * cg + c;
            float bcol = (col < DD) ? bias[col] : 0.f;
#pragma unroll
            for (int r = 0; r < 4; ++r) {
                int row = rb + 16 * qg + 4 * g + r;
                float v = acc[qg][cg][r] + bcol;
                if constexpr (F16OUT) {
                    ((_Float16*)Cout)[(size_t)row * DP + col] = (_Float16)v;
                } else {
                    if (col < DD) ((float*)Cout)[(size_t)row * DD + col] = v;
                }
            }
        }
}

// ---------------- stats: per row M (full max), alpha ----------------
__global__ __launch_bounds__(64) void stats16(const _Float16* __restrict__ Qb,
                                              const _Float16* __restrict__ Kb,
                                              const float* __restrict__ valence,
                                              float* __restrict__ rowstats) {
    int l = threadIdx.x, c = l & 15, g = l >> 4;
    int bx = blockIdx.x, b = blockIdx.y;
    size_t bN = (size_t)b * NN;
    int n0 = bx * 32;
    half8 qf[2][KC];
#pragma unroll
    for (int qg = 0; qg < 2; ++qg)
#pragma unroll
        for (int kc = 0; kc < KC; ++kc)
            qf[qg][kc] = *(const half8*)(Qb + (bN + n0 + 16 * qg + c) * FSP + kc * 32 + g * 8);
    int n[2] = {n0 + c, n0 + 16 + c};
    float M[2] = {-1e30f, -1e30f}, F[2] = {0.f, 0.f}, S[2] = {0.f, 0.f};
    for (int m0 = 0; m0 < NN; m0 += 32) {
        half8 kf[2][KC];
#pragma unroll
        for (int s = 0; s < 2; ++s)
#pragma unroll
            for (int kc = 0; kc < KC; ++kc)
                kf[s][kc] = *(const half8*)(Kb + (bN + m0 + 16 * s + c) * FSP + kc * 32 + g * 8);
#pragma unroll
        for (int qg = 0; qg < 2; ++qg) {
            float sv[8];
#pragma unroll
            for (int s = 0; s < 2; ++s) {
                float4v p = (float4v){0.f, 0.f, 0.f, 0.f};
#pragma unroll
                for (int kc = 0; kc < KC; ++kc) p = MFMA16(kf[s][kc], qf[qg][kc], p, 0, 0, 0);
#pragma unroll
                for (int r = 0; r < 4; ++r) {
                    int m = m0 + 16 * s + 4 * g + r;
                    sv[4 * s + r] = p[r] - 0.3f * fabsf((float)(n[qg] - m));
                }
            }
            float t = sv[0];
#pragma unroll
            for (int i = 1; i < 8; ++i) t = fmaxf(t, sv[i]);
            float Mn = fmaxf(M[qg], t);
            float corr = __expf(M[qg] - Mn);
            F[qg] *= corr; S[qg] *= corr; M[qg] = Mn;
#pragma unroll
            for (int s = 0; s < 2; ++s)
#pragma unroll
                for (int r = 0; r < 4; ++r) {
                    int m = m0 + 16 * s + 4 * g + r;
                    float e = __expf(sv[4 * s + r] - M[qg]);
                    F[qg] += e;
                    S[qg] += (m <= n[qg]) ? e : 0.f;
                }
        }
    }
    // merge across the 4 lane-groups (lanes c, c+16, c+32, c+48 share row n)
#pragma unroll
    for (int qg = 0; qg < 2; ++qg) {
#pragma unroll
        for (int off = 16; off <= 32; off <<= 1) {
            float Mo = __shfl_xor(M[qg], off);
            float Fo = __shfl_xor(F[qg], off);
            float So = __shfl_xor(S[qg], off);
            float Mn = fmaxf(M[qg], Mo);
            float ca = __expf(M[qg] - Mn), cb2 = __expf(Mo - Mn);
            F[qg] = F[qg] * ca + Fo * cb2;
            S[qg] = S[qg] * ca + So * cb2;
            M[qg] = Mn;
        }
    }
    if (l < 32) {
        int qg = g;  // l<16 -> qg0, 16..31 -> qg1
        int nn = n0 + 16 * qg + c;
        float val = valence[bN + nn];
        float scale = fminf(val / (1.0f + 1e-6f), 1.0f);
        float alpha = scale / (scale * S[qg] + 1e-8f * F[qg]);
        rowstats[(bN + nn) * 2 + 0] = M[qg];
        rowstats[(bN + nn) * 2 + 1] = alpha;
    }
}

// ---------------- PV: O[n][d] = alpha * sum_{m<=n} exp(s-M) * V[m][d] ----------------
__global__ __launch_bounds__(64) void pv16(const _Float16* __restrict__ Qb,
                                           const _Float16* __restrict__ Kb,
                                           const _Float16* __restrict__ Vt,
                                           const float* __restrict__ rowstats,
                                           _Float16* __restrict__ Oh) {
    __shared__ __align__(16) uint Plds[2][16][20];  // [qg][n'][m'-dword], stride 20 dw
    int l = threadIdx.x, c = l & 15, g = l >> 4;
    int bx = blockIdx.x, b = blockIdx.y;
    size_t bN = (size_t)b * NN;
    int n0 = bx * 32;
    half8 qf[2][KC];
#pragma unroll
    for (int qg = 0; qg < 2; ++qg)
#pragma unroll
        for (int kc = 0; kc < KC; ++kc)
            qf[qg][kc] = *(const half8*)(Qb + (bN + n0 + 16 * qg + c) * FSP + kc * 32 + g * 8);
    int n[2] = {n0 + c, n0 + 16 + c};
    float Mq[2], Aq[2];
#pragma unroll
    for (int qg = 0; qg < 2; ++qg) {
        Mq[qg] = rowstats[(bN + n0 + 16 * qg + c) * 2 + 0];
        Aq[qg] = rowstats[(bN + n0 + 16 * qg + c) * 2 + 1];
    }
    float4v acc[2][16];
#pragma unroll
    for (int qg = 0; qg < 2; ++qg)
#pragma unroll
        for (int dc = 0; dc < 16; ++dc) acc[qg][dc] = (float4v){0.f, 0.f, 0.f, 0.f};
    const _Float16* VtB = Vt + (size_t)b * DP * NN;

    for (int t = 0; t <= bx; ++t) {
        int m0 = 32 * t;
        half8 kf[2][KC];
#pragma unroll
        for (int s = 0; s < 2; ++s)
#pragma unroll
            for (int kc = 0; kc < KC; ++kc)
                kf[s][kc] = *(const half8*)(Kb + (bN + m0 + 16 * s + c) * FSP + kc * 32 + g * 8);
#pragma unroll
        for (int qg = 0; qg < 2; ++qg) {
#pragma unroll
            for (int s = 0; s < 2; ++s) {
                float4v p = (float4v){0.f, 0.f, 0.f, 0.f};
#pragma unroll
                for (int kc = 0; kc < KC; ++kc) p = MFMA16(kf[s][kc], qf[qg][kc], p, 0, 0, 0);
                float w[4];
#pragma unroll
                for (int r = 0; r < 4; ++r) {
                    int m = m0 + 16 * s + 4 * g + r;
                    float sc = p[r] - 0.3f * fabsf((float)(n[qg] - m));
                    w[r] = (m <= n[qg]) ? __expf(sc - Mq[qg]) : 0.f;
                }
                uint* dst = &Plds[qg][c][8 * s + 2 * g];
                dst[0] = pack2(w[0], w[1]);
                dst[1] = pack2(w[2], w[3]);
            }
        }
        half8 pa[2];
        pa[0] = *(const half8*)&Plds[0][c][4 * g];
        pa[1] = *(const half8*)&Plds[1][c][4 * g];
#pragma unroll
        for (int dc = 0; dc < 16; ++dc) {
            half8 vf = *(const half8*)(VtB + (size_t)(dc * 16 + c) * NN + m0 + g * 8);
            acc[0][dc] = MFMA16(pa[0], vf, acc[0][dc], 0, 0, 0);
            acc[1][dc] = MFMA16(pa[1], vf, acc[1][dc], 0, 0, 0);
        }
    }
    // epilogue: O rows live at row-index 4g+r, col c; fetch alpha via shuffle
#pragma unroll
    for (int qg = 0; qg < 2; ++qg)
#pragma unroll
        for (int r = 0; r < 4; ++r) {
            float a = __shfl(Aq[qg], 4 * g + r);
            int nn = n0 + 16 * qg + 4 * g + r;
#pragma unroll
            for (int dc = 0; dc < 16; ++dc)
                Oh[(bN + nn) * DP + dc * 16 + c] = (_Float16)(a * acc[qg][dc][r]);
        }
}

// ---------------- launch ----------------
extern "C" void kernel_launch(void* const* d_in, const int* in_sizes, int n_in,
                              void* d_out, int out_size, void* d_ws, size_t ws_size,
                              hipStream_t stream) {
    (void)in_sizes; (void)n_in; (void)out_size; (void)ws_size;
    const float* charge  = (const float*)d_in[0];
    const float* shell   = (const float*)d_in[1];
    const float* mass    = (const float*)d_in[2];
    const float* valence = (const float*)d_in[3];
    const float* x  = (const float*)d_in[5];
    const float* Wv = (const float*)d_in[6];
    const float* bv = (const float*)d_in[7];
    const float* Wo = (const float*)d_in[8];
    const float* bo = (const float*)d_in[9];
    float* out = (float*)d_out;

    const size_t BN = (size_t)BB * NN;
    char* w = (char*)d_ws;
    _Float16* Qb  = (_Float16*)w;              w += BN * FSP * 2;   // 3.1 MB
    _Float16* Kb  = (_Float16*)w;              w += BN * FSP * 2;   // 3.1 MB
    _Float16* xh  = (_Float16*)w;              w += BN * DP * 2;    // 8.4 MB (reused as Oh)
    _Float16* Vh  = (_Float16*)w;              w += BN * DP * 2;    // 8.4 MB
    _Float16* Vt  = (_Float16*)w;              w += BN * DP * 2;    // 8.4 MB
    _Float16* Wvh = (_Float16*)w;              w += DP * DP * 2;
    _Float16* Woh = (_Float16*)w;              w += DP * DP * 2;
    float* rowstats = (float*)w;               w += BN * 2 * 4;
    _Float16* Oh = xh;  // xh dead after V-GEMM

    prep_x<<<BB * NN, 256, 0, stream>>>(x, xh);
    prep_w<<<dim3(DP, 2), 256, 0, stream>>>(Wv, Wo, Wvh, Woh);
    prep_feat<<<BB * NN, 64, 0, stream>>>(charge, shell, mass, Qb, Kb);
    gemm16<true><<<dim3(BB * NN / 32, DP / 32), 64, 0, stream>>>(xh, Wvh, bv, (void*)Vh);
    transpose_v<<<dim3(NN / 64, DP / 64, BB), 256, 0, stream>>>(Vh, Vt);
    stats16<<<dim3(NN / 32, BB), 64, 0, stream>>>(Qb, Kb, valence, rowstats);
    pv16<<<dim3(NN / 32, BB), 64, 0, stream>>>(Qb, Kb, Vt, rowstats, Oh);
    gemm16<false><<<dim3(BB * NN / 32, DP / 32), 64, 0, stream>>>(Oh, Woh, bo, (void*)out);
}

// Round 4
// 324.297 us; speedup vs baseline: 3.7232x; 1.8091x over previous
//
#include <hip/hip_runtime.h>
#include <cmath>

#define BB 4
#define NN 4096
#define DD 244
#define DP 256
#define FSP 96
#define KC 3       // FSP/32 k-chunks for scores
#define MSPLIT 16  // m-chunks for stats
#define TPC ((NN / 32) / MSPLIT)  // tiles per stats chunk = 8
#define WV 4       // waves per pv block

typedef _Float16 half8 __attribute__((ext_vector_type(8)));
typedef float float4v __attribute__((ext_vector_type(4)));
typedef unsigned int uint;

#define MFMA16 __builtin_amdgcn_mfma_f32_16x16x32_f16

static __device__ __forceinline__ uint pack2(float a, float b) {
    _Float16 ha = (_Float16)a, hb = (_Float16)b;
    unsigned short ua = __builtin_bit_cast(unsigned short, ha);
    unsigned short ub = __builtin_bit_cast(unsigned short, hb);
    return (uint)ua | ((uint)ub << 16);
}

// ---------------- prep kernels ----------------
__global__ __launch_bounds__(256) void prep_x(const float* __restrict__ x,
                                              _Float16* __restrict__ xh) {
    size_t i = blockIdx.x; int k = threadIdx.x;
    xh[i * DP + k] = (k < DD) ? (_Float16)x[i * DD + k] : (_Float16)0.f;
}

__global__ __launch_bounds__(256) void prep_w(const float* __restrict__ Wv,
                                              const float* __restrict__ Wo,
                                              _Float16* __restrict__ Wvh,
                                              _Float16* __restrict__ Woh) {
    int r = blockIdx.x, k = threadIdx.x;
    const float* src = blockIdx.y ? Wo : Wv;
    _Float16* dst = blockIdx.y ? Woh : Wvh;
    dst[(size_t)r * DP + k] =
        (r < DD && k < DD) ? (_Float16)src[(size_t)r * DD + k] : (_Float16)0.f;
}

// feature order: k 0..63 = shell, 64 = charge, 65 = sqrt(mass), 66..95 = 0
// Qb = -weight * feat  (so score = dot(Qb_n, Kb_m) - 0.3|n-m| = -energy)
__global__ __launch_bounds__(64) void prep_feat(const float* __restrict__ charge,
                                                const float* __restrict__ shell,
                                                const float* __restrict__ mass,
                                                _Float16* __restrict__ Qb,
                                                _Float16* __restrict__ Kb) {
    size_t row = blockIdx.x; int t = threadIdx.x;
    float v = shell[row * 64 + t];
    Kb[row * FSP + t] = (_Float16)v;
    Qb[row * FSP + t] = (_Float16)(-0.5f * v);
    int k2 = 64 + t;
    if (k2 < FSP) {
        float v2 = 0.f, q2 = 0.f;
        if (t == 0) { v2 = charge[row]; q2 = -1.0f * v2; }
        else if (t == 1) { v2 = sqrtf(mass[row]); q2 = -0.1f * v2; }
        Kb[row * FSP + k2] = (_Float16)v2;
        Qb[row * FSP + k2] = (_Float16)q2;
    }
}

// Vh [B*N][DP] f16 -> Vt [B][DP][N] f16
__global__ __launch_bounds__(256) void transpose_v(const _Float16* __restrict__ Vh,
                                                   _Float16* __restrict__ Vt) {
    __shared__ _Float16 tile[64][65];
    int n0 = blockIdx.x * 64, d0 = blockIdx.y * 64, b = blockIdx.z;
    int t = threadIdx.x;
#pragma unroll
    for (int i = 0; i < 16; ++i) {
        int idx = t + 256 * i;
        int r = idx >> 6, cc = idx & 63;
        tile[r][cc] = Vh[(size_t)(b * NN + n0 + r) * DP + d0 + cc];
    }
    __syncthreads();
#pragma unroll
    for (int i = 0; i < 16; ++i) {
        int idx = t + 256 * i;
        int dr = idx >> 6, nc = idx & 63;
        Vt[(size_t)b * DP * NN + (size_t)(d0 + dr) * NN + n0 + nc] = tile[nc][dr];
    }
}

// ---------------- f16 MFMA GEMM: C[r][c] = sum_k A[r][k]*W[c][k] + bias[c] ----------------
template <bool F16OUT>
__global__ __launch_bounds__(64) void gemm16(const _Float16* __restrict__ A,
                                             const _Float16* __restrict__ W,
                                             const float* __restrict__ bias,
                                             void* __restrict__ Cout) {
    int l = threadIdx.x, c = l & 15, g = l >> 4;
    int rb = blockIdx.x * 32, cb = blockIdx.y * 32;
    float4v acc[2][2];
#pragma unroll
    for (int i = 0; i < 2; ++i)
#pragma unroll
        for (int j = 0; j < 2; ++j) acc[i][j] = (float4v){0.f, 0.f, 0.f, 0.f};
#pragma unroll
    for (int kc = 0; kc < 8; ++kc) {
        half8 af[2], bf[2];
#pragma unroll
        for (int i = 0; i < 2; ++i) {
            af[i] = *(const half8*)(A + (size_t)(rb + 16 * i + c) * DP + kc * 32 + g * 8);
            bf[i] = *(const half8*)(W + (size_t)(cb + 16 * i + c) * DP + kc * 32 + g * 8);
        }
#pragma unroll
        for (int qg = 0; qg < 2; ++qg)
#pragma unroll
            for (int cg = 0; cg < 2; ++cg)
                acc[qg][cg] = MFMA16(af[qg], bf[cg], acc[qg][cg], 0, 0, 0);
    }
#pragma unroll
    for (int qg = 0; qg < 2; ++qg)
#pragma unroll
        for (int cg = 0; cg < 2; ++cg) {
            int col = cb + 16 * cg + c;
            float bcol = (col < DD) ? bias[col] : 0.f;
#pragma unroll
            for (int r = 0; r < 4; ++r) {
                int row = rb + 16 * qg + 4 * g + r;
                float v = acc[qg][cg][r] + bcol;
                if constexpr (F16OUT) {
                    ((_Float16*)Cout)[(size_t)row * DP + col] = (_Float16)v;
                } else {
                    if (col < DD) ((float*)Cout)[(size_t)row * DD + col] = v;
                }
            }
        }
}

// ---------------- stats stage A: per (row, m-chunk) partial (M, F, S) ----------------
__global__ __launch_bounds__(64) void stats_partial(const _Float16* __restrict__ Qb,
                                                    const _Float16* __restrict__ Kb,
                                                    float* __restrict__ partP) {
    int l = threadIdx.x, c = l & 15, g = l >> 4;
    int bx = blockIdx.x, chunk = blockIdx.y, b = blockIdx.z;
    size_t bN = (size_t)b * NN;
    int n0 = bx * 32;
    half8 qf[2][KC];
#pragma unroll
    for (int qg = 0; qg < 2; ++qg)
#pragma unroll
        for (int kc = 0; kc < KC; ++kc)
            qf[qg][kc] = *(const half8*)(Qb + (bN + n0 + 16 * qg + c) * FSP + kc * 32 + g * 8);
    int n[2] = {n0 + c, n0 + 16 + c};
    float M[2] = {-1e30f, -1e30f}, F[2] = {0.f, 0.f}, S[2] = {0.f, 0.f};
    int m_lo = chunk * TPC * 32, m_hi = m_lo + TPC * 32;
    for (int m0 = m_lo; m0 < m_hi; m0 += 32) {
        half8 kf[2][KC];
#pragma unroll
        for (int s = 0; s < 2; ++s)
#pragma unroll
            for (int kc = 0; kc < KC; ++kc)
                kf[s][kc] = *(const half8*)(Kb + (bN + m0 + 16 * s + c) * FSP + kc * 32 + g * 8);
#pragma unroll
        for (int qg = 0; qg < 2; ++qg) {
            float sv[8];
#pragma unroll
            for (int s = 0; s < 2; ++s) {
                float4v p = (float4v){0.f, 0.f, 0.f, 0.f};
#pragma unroll
                for (int kc = 0; kc < KC; ++kc) p = MFMA16(kf[s][kc], qf[qg][kc], p, 0, 0, 0);
#pragma unroll
                for (int r = 0; r < 4; ++r) {
                    int m = m0 + 16 * s + 4 * g + r;
                    sv[4 * s + r] = p[r] - 0.3f * fabsf((float)(n[qg] - m));
                }
            }
            float t = sv[0];
#pragma unroll
            for (int i = 1; i < 8; ++i) t = fmaxf(t, sv[i]);
            float Mn = fmaxf(M[qg], t);
            float corr = __expf(M[qg] - Mn);
            F[qg] *= corr; S[qg] *= corr; M[qg] = Mn;
#pragma unroll
            for (int s = 0; s < 2; ++s)
#pragma unroll
                for (int r = 0; r < 4; ++r) {
                    int m = m0 + 16 * s + 4 * g + r;
                    float e = __expf(sv[4 * s + r] - M[qg]);
                    F[qg] += e;
                    S[qg] += (m <= n[qg]) ? e : 0.f;
                }
        }
    }
    // merge across the 4 lane-groups (lanes c, c+16, c+32, c+48 share row n)
#pragma unroll
    for (int qg = 0; qg < 2; ++qg) {
#pragma unroll
        for (int off = 16; off <= 32; off <<= 1) {
            float Mo = __shfl_xor(M[qg], off);
            float Fo = __shfl_xor(F[qg], off);
            float So = __shfl_xor(S[qg], off);
            float Mn = fmaxf(M[qg], Mo);
            float ca = __expf(M[qg] - Mn), cb2 = __expf(Mo - Mn);
            F[qg] = F[qg] * ca + Fo * cb2;
            S[qg] = S[qg] * ca + So * cb2;
            M[qg] = Mn;
        }
    }
    if (l < 32) {
        int qg = g;  // l<16 -> qg0, 16..31 -> qg1
        size_t bn = bN + n0 + 16 * qg + c;
        size_t idx = ((size_t)chunk * (BB * NN) + bn) * 3;
        partP[idx + 0] = M[qg];
        partP[idx + 1] = F[qg];
        partP[idx + 2] = S[qg];
    }
}

// ---------------- stats stage B: merge chunks, compute alpha ----------------
__global__ __launch_bounds__(256) void stats_merge(const float* __restrict__ partP,
                                                   const float* __restrict__ valence,
                                                   float* __restrict__ rowstats) {
    size_t bn = (size_t)blockIdx.x * 256 + threadIdx.x;
    float M = -1e30f, F = 0.f, S = 0.f;
#pragma unroll
    for (int ch = 0; ch < MSPLIT; ++ch) {
        size_t idx = ((size_t)ch * (BB * NN) + bn) * 3;
        float m = partP[idx + 0], f = partP[idx + 1], s = partP[idx + 2];
        float Mn = fmaxf(M, m);
        float ca = __expf(M - Mn), cb2 = __expf(m - Mn);
        F = F * ca + f * cb2;
        S = S * ca + s * cb2;
        M = Mn;
    }
    float val = valence[bn];
    float scale = fminf(val / (1.0f + 1e-6f), 1.0f);
    float alpha = scale / (scale * S + 1e-8f * F);
    rowstats[bn * 2 + 0] = M;
    rowstats[bn * 2 + 1] = alpha;
}

// ---------------- PV: 4 waves; wave w scores tile ro*4+w -> LDS; all waves
// contract all 4 P-tiles against their own dc-quarter of Vt (no merge) -------
__global__ __launch_bounds__(256) void pv16(const _Float16* __restrict__ Qb,
                                            const _Float16* __restrict__ Kb,
                                            const _Float16* __restrict__ Vt,
                                            const float* __restrict__ rowstats,
                                            _Float16* __restrict__ Oh) {
    __shared__ __align__(16) uint Plds[2][WV][2][16][20];  // [buf][wave][qg][n'][m'-dw]
    int t = threadIdx.x;
    int w = t >> 6, l = t & 63, c = l & 15, g = l >> 4;
    int xx = blockIdx.x;
    // pairing swizzle: big and small causal blocks alternate in dispatch order
    int bx = (xx & 1) ? (NN / 32 - 1 - (xx >> 1)) : (xx >> 1);
    int b = blockIdx.y;
    size_t bN = (size_t)b * NN;
    int n0 = bx * 32;
    half8 qf[2][KC];
#pragma unroll
    for (int qg = 0; qg < 2; ++qg)
#pragma unroll
        for (int kc = 0; kc < KC; ++kc)
            qf[qg][kc] = *(const half8*)(Qb + (bN + n0 + 16 * qg + c) * FSP + kc * 32 + g * 8);
    int nq[2] = {n0 + c, n0 + 16 + c};
    float Mq[2], Aq[2];
#pragma unroll
    for (int qg = 0; qg < 2; ++qg) {
        Mq[qg] = rowstats[(bN + n0 + 16 * qg + c) * 2 + 0];
        Aq[qg] = rowstats[(bN + n0 + 16 * qg + c) * 2 + 1];
    }
    float4v acc[2][4];
#pragma unroll
    for (int qg = 0; qg < 2; ++qg)
#pragma unroll
        for (int d = 0; d < 4; ++d) acc[qg][d] = (float4v){0.f, 0.f, 0.f, 0.f};
    const _Float16* VtB = Vt + (size_t)b * DP * NN;

    int nt = bx + 1;
    int rounds = (nt + WV - 1) / WV;
    for (int ro = 0; ro < rounds; ++ro) {
        int bufi = ro & 1;
        int tt = ro * WV + w;
        if (tt < nt) {
            int m0 = tt * 32;
            half8 kf[2][KC];
#pragma unroll
            for (int s = 0; s < 2; ++s)
#pragma unroll
                for (int kc = 0; kc < KC; ++kc)
                    kf[s][kc] = *(const half8*)(Kb + (bN + m0 + 16 * s + c) * FSP + kc * 32 + g * 8);
#pragma unroll
            for (int qg = 0; qg < 2; ++qg) {
#pragma unroll
                for (int s = 0; s < 2; ++s) {
                    float4v p = (float4v){0.f, 0.f, 0.f, 0.f};
#pragma unroll
                    for (int kc = 0; kc < KC; ++kc) p = MFMA16(kf[s][kc], qf[qg][kc], p, 0, 0, 0);
                    float wv[4];
#pragma unroll
                    for (int r = 0; r < 4; ++r) {
                        int m = m0 + 16 * s + 4 * g + r;
                        float sc = p[r] - 0.3f * fabsf((float)(nq[qg] - m));
                        wv[r] = (m <= nq[qg]) ? __expf(sc - Mq[qg]) : 0.f;
                    }
                    uint* dst = &Plds[bufi][w][qg][c][8 * s + 2 * g];
                    dst[0] = pack2(wv[0], wv[1]);
                    dst[1] = pack2(wv[2], wv[3]);
                }
            }
        }
        __syncthreads();
        int lim = (nt - ro * WV < WV) ? (nt - ro * WV) : WV;
        for (int ww = 0; ww < lim; ++ww) {
            int m0p = (ro * WV + ww) * 32;
            half8 pa0 = *(const half8*)&Plds[bufi][ww][0][c][4 * g];
            half8 pa1 = *(const half8*)&Plds[bufi][ww][1][c][4 * g];
#pragma unroll
            for (int dcl = 0; dcl < 4; ++dcl) {
                int dc = 4 * w + dcl;
                half8 vf = *(const half8*)(VtB + (size_t)(dc * 16 + c) * NN + m0p + g * 8);
                acc[0][dcl] = MFMA16(pa0, vf, acc[0][dcl], 0, 0, 0);
                acc[1][dcl] = MFMA16(pa1, vf, acc[1][dcl], 0, 0, 0);
            }
        }
    }
    // epilogue: row nn = n0+16qg+4g+r, col (4w+dcl)*16 + c; alpha via intra-wave shuffle
#pragma unroll
    for (int qg = 0; qg < 2; ++qg)
#pragma unroll
        for (int r = 0; r < 4; ++r) {
            float a = __shfl(Aq[qg], 4 * g + r);
            int nn = n0 + 16 * qg + 4 * g + r;
#pragma unroll
            for (int dcl = 0; dcl < 4; ++dcl)
                Oh[(bN + nn) * DP + (4 * w + dcl) * 16 + c] = (_Float16)(a * acc[qg][dcl][r]);
        }
}

// ---------------- launch ----------------
extern "C" void kernel_launch(void* const* d_in, const int* in_sizes, int n_in,
                              void* d_out, int out_size, void* d_ws, size_t ws_size,
                              hipStream_t stream) {
    (void)in_sizes; (void)n_in; (void)out_size; (void)ws_size;
    const float* charge  = (const float*)d_in[0];
    const float* shell   = (const float*)d_in[1];
    const float* mass    = (const float*)d_in[2];
    const float* valence = (const float*)d_in[3];
    const float* x  = (const float*)d_in[5];
    const float* Wv = (const float*)d_in[6];
    const float* bv = (const float*)d_in[7];
    const float* Wo = (const float*)d_in[8];
    const float* bo = (const float*)d_in[9];
    float* out = (float*)d_out;

    const size_t BN = (size_t)BB * NN;
    char* w = (char*)d_ws;
    _Float16* Qb  = (_Float16*)w;              w += BN * FSP * 2;   // 3.1 MB
    _Float16* Kb  = (_Float16*)w;              w += BN * FSP * 2;   // 3.1 MB
    _Float16* xh  = (_Float16*)w;              w += BN * DP * 2;    // 8.4 MB (reused as Oh)
    _Float16* Vh  = (_Float16*)w;              w += BN * DP * 2;    // 8.4 MB
    _Float16* Vt  = (_Float16*)w;              w += BN * DP * 2;    // 8.4 MB
    _Float16* Wvh = (_Float16*)w;              w += DP * DP * 2;
    _Float16* Woh = (_Float16*)w;              w += DP * DP * 2;
    float* rowstats = (float*)w;               w += BN * 2 * 4;
    float* partP    = (float*)w;               w += (size_t)MSPLIT * BN * 3 * 4;  // 3.1 MB
    _Float16* Oh = xh;  // xh dead after V-GEMM

    prep_x<<<BB * NN, 256, 0, stream>>>(x, xh);
    prep_w<<<dim3(DP, 2), 256, 0, stream>>>(Wv, Wo, Wvh, Woh);
    prep_feat<<<BB * NN, 64, 0, stream>>>(charge, shell, mass, Qb, Kb);
    gemm16<true><<<dim3(BB * NN / 32, DP / 32), 64, 0, stream>>>(xh, Wvh, bv, (void*)Vh);
    transpose_v<<<dim3(NN / 64, DP / 64, BB), 256, 0, stream>>>(Vh, Vt);
    stats_partial<<<dim3(NN / 32, MSPLIT, BB), 64, 0, stream>>>(Qb, Kb, partP);
    stats_merge<<<BN / 256, 256, 0, stream>>>(partP, valence, rowstats);
    pv16<<<dim3(NN / 32, BB), 256, 0, stream>>>(Qb, Kb, Vt, rowstats, Oh);
    gemm16<false><<<dim3(BB * NN / 32, DP / 32), 64, 0, stream>>>(Oh, Woh, bo, (void*)out);
}

// Round 5
// 291.441 us; speedup vs baseline: 4.1429x; 1.1127x over previous
//
#include <hip/hip_runtime.h>
#include <cmath>

#define BB 4
#define NN 4096
#define DD 244
#define DP 256
#define FSP 96
#define KC 3       // FSP/32 k-chunks for scores
#define MSPLIT 16  // m-chunks for stats
#define TPC ((NN / 32) / MSPLIT)  // tiles per stats chunk = 8
#define WV 4       // waves per pv block

typedef _Float16 half8 __attribute__((ext_vector_type(8)));
typedef float float4v __attribute__((ext_vector_type(4)));
typedef unsigned int uint;

#define MFMA16 __builtin_amdgcn_mfma_f32_16x16x32_f16

static __device__ __forceinline__ uint pack2(float a, float b) {
    _Float16 ha = (_Float16)a, hb = (_Float16)b;
    unsigned short ua = __builtin_bit_cast(unsigned short, ha);
    unsigned short ub = __builtin_bit_cast(unsigned short, hb);
    return (uint)ua | ((uint)ub << 16);
}

// ---------------- prep kernels ----------------
__global__ __launch_bounds__(256) void prep_x(const float* __restrict__ x,
                                              _Float16* __restrict__ xh) {
    size_t i = blockIdx.x; int k = threadIdx.x;
    xh[i * DP + k] = (k < DD) ? (_Float16)x[i * DD + k] : (_Float16)0.f;
}

__global__ __launch_bounds__(256) void prep_w(const float* __restrict__ Wv,
                                              const float* __restrict__ Wo,
                                              _Float16* __restrict__ Wvh,
                                              _Float16* __restrict__ Woh) {
    int r = blockIdx.x, k = threadIdx.x;
    const float* src = blockIdx.y ? Wo : Wv;
    _Float16* dst = blockIdx.y ? Woh : Wvh;
    dst[(size_t)r * DP + k] =
        (r < DD && k < DD) ? (_Float16)src[(size_t)r * DD + k] : (_Float16)0.f;
}

// feature order: k 0..63 = shell, 64 = charge, 65 = sqrt(mass), 66..95 = 0
// Qb = -weight * feat  (so score = dot(Qb_n, Kb_m) - 0.3|n-m| = -energy)
__global__ __launch_bounds__(64) void prep_feat(const float* __restrict__ charge,
                                                const float* __restrict__ shell,
                                                const float* __restrict__ mass,
                                                _Float16* __restrict__ Qb,
                                                _Float16* __restrict__ Kb) {
    size_t row = blockIdx.x; int t = threadIdx.x;
    float v = shell[row * 64 + t];
    Kb[row * FSP + t] = (_Float16)v;
    Qb[row * FSP + t] = (_Float16)(-0.5f * v);
    int k2 = 64 + t;
    if (k2 < FSP) {
        float v2 = 0.f, q2 = 0.f;
        if (t == 0) { v2 = charge[row]; q2 = -1.0f * v2; }
        else if (t == 1) { v2 = sqrtf(mass[row]); q2 = -0.1f * v2; }
        Kb[row * FSP + k2] = (_Float16)v2;
        Qb[row * FSP + k2] = (_Float16)q2;
    }
}

// Vh [B*N][DP] f16 -> Vt [B][DP][N] f16
__global__ __launch_bounds__(256) void transpose_v(const _Float16* __restrict__ Vh,
                                                   _Float16* __restrict__ Vt) {
    __shared__ _Float16 tile[64][65];
    int n0 = blockIdx.x * 64, d0 = blockIdx.y * 64, b = blockIdx.z;
    int t = threadIdx.x;
#pragma unroll
    for (int i = 0; i < 16; ++i) {
        int idx = t + 256 * i;
        int r = idx >> 6, cc = idx & 63;
        tile[r][cc] = Vh[(size_t)(b * NN + n0 + r) * DP + d0 + cc];
    }
    __syncthreads();
#pragma unroll
    for (int i = 0; i < 16; ++i) {
        int idx = t + 256 * i;
        int dr = idx >> 6, nc = idx & 63;
        Vt[(size_t)b * DP * NN + (size_t)(d0 + dr) * NN + n0 + nc] = tile[nc][dr];
    }
}

// ---------------- f16 MFMA GEMM: C[r][c] = sum_k A[r][k]*W[c][k] + bias[c] ----------------
template <bool F16OUT>
__global__ __launch_bounds__(64) void gemm16(const _Float16* __restrict__ A,
                                             const _Float16* __restrict__ W,
                                             const float* __restrict__ bias,
                                             void* __restrict__ Cout) {
    int l = threadIdx.x, c = l & 15, g = l >> 4;
    int rb = blockIdx.x * 32, cb = blockIdx.y * 32;
    float4v acc[2][2];
#pragma unroll
    for (int i = 0; i < 2; ++i)
#pragma unroll
        for (int j = 0; j < 2; ++j) acc[i][j] = (float4v){0.f, 0.f, 0.f, 0.f};
#pragma unroll
    for (int kc = 0; kc < 8; ++kc) {
        half8 af[2], bf[2];
#pragma unroll
        for (int i = 0; i < 2; ++i) {
            af[i] = *(const half8*)(A + (size_t)(rb + 16 * i + c) * DP + kc * 32 + g * 8);
            bf[i] = *(const half8*)(W + (size_t)(cb + 16 * i + c) * DP + kc * 32 + g * 8);
        }
#pragma unroll
        for (int qg = 0; qg < 2; ++qg)
#pragma unroll
            for (int cg = 0; cg < 2; ++cg)
                acc[qg][cg] = MFMA16(af[qg], bf[cg], acc[qg][cg], 0, 0, 0);
    }
#pragma unroll
    for (int qg = 0; qg < 2; ++qg)
#pragma unroll
        for (int cg = 0; cg < 2; ++cg) {
            int col = cb + 16 * cg + c;
            float bcol = (col < DD) ? bias[col] : 0.f;
#pragma unroll
            for (int r = 0; r < 4; ++r) {
                int row = rb + 16 * qg + 4 * g + r;
                float v = acc[qg][cg][r] + bcol;
                if constexpr (F16OUT) {
                    ((_Float16*)Cout)[(size_t)row * DP + col] = (_Float16)v;
                } else {
                    if (col < DD) ((float*)Cout)[(size_t)row * DD + col] = v;
                }
            }
        }
}

// ---------------- stats stage A: per (row, m-chunk) partial (M, F, S) ----------------
__global__ __launch_bounds__(64) void stats_partial(const _Float16* __restrict__ Qb,
                                                    const _Float16* __restrict__ Kb,
                                                    float* __restrict__ partP) {
    int l = threadIdx.x, c = l & 15, g = l >> 4;
    int bx = blockIdx.x, chunk = blockIdx.y, b = blockIdx.z;
    size_t bN = (size_t)b * NN;
    int n0 = bx * 32;
    half8 qf[2][KC];
#pragma unroll
    for (int qg = 0; qg < 2; ++qg)
#pragma unroll
        for (int kc = 0; kc < KC; ++kc)
            qf[qg][kc] = *(const half8*)(Qb + (bN + n0 + 16 * qg + c) * FSP + kc * 32 + g * 8);
    int n[2] = {n0 + c, n0 + 16 + c};
    float M[2] = {-1e30f, -1e30f}, F[2] = {0.f, 0.f}, S[2] = {0.f, 0.f};
    int m_lo = chunk * TPC * 32, m_hi = m_lo + TPC * 32;
    for (int m0 = m_lo; m0 < m_hi; m0 += 32) {
        half8 kf[2][KC];
#pragma unroll
        for (int s = 0; s < 2; ++s)
#pragma unroll
            for (int kc = 0; kc < KC; ++kc)
                kf[s][kc] = *(const half8*)(Kb + (bN + m0 + 16 * s + c) * FSP + kc * 32 + g * 8);
#pragma unroll
        for (int qg = 0; qg < 2; ++qg) {
            float sv[8];
#pragma unroll
            for (int s = 0; s < 2; ++s) {
                float4v p = (float4v){0.f, 0.f, 0.f, 0.f};
#pragma unroll
                for (int kc = 0; kc < KC; ++kc) p = MFMA16(kf[s][kc], qf[qg][kc], p, 0, 0, 0);
#pragma unroll
                for (int r = 0; r < 4; ++r) {
                    int m = m0 + 16 * s + 4 * g + r;
                    sv[4 * s + r] = p[r] - 0.3f * fabsf((float)(n[qg] - m));
                }
            }
            float t = sv[0];
#pragma unroll
            for (int i = 1; i < 8; ++i) t = fmaxf(t, sv[i]);
            float Mn = fmaxf(M[qg], t);
            float corr = __expf(M[qg] - Mn);
            F[qg] *= corr; S[qg] *= corr; M[qg] = Mn;
#pragma unroll
            for (int s = 0; s < 2; ++s)
#pragma unroll
                for (int r = 0; r < 4; ++r) {
                    int m = m0 + 16 * s + 4 * g + r;
                    float e = __expf(sv[4 * s + r] - M[qg]);
                    F[qg] += e;
                    S[qg] += (m <= n[qg]) ? e : 0.f;
                }
        }
    }
#pragma unroll
    for (int qg = 0; qg < 2; ++qg) {
#pragma unroll
        for (int off = 16; off <= 32; off <<= 1) {
            float Mo = __shfl_xor(M[qg], off);
            float Fo = __shfl_xor(F[qg], off);
            float So = __shfl_xor(S[qg], off);
            float Mn = fmaxf(M[qg], Mo);
            float ca = __expf(M[qg] - Mn), cb2 = __expf(Mo - Mn);
            F[qg] = F[qg] * ca + Fo * cb2;
            S[qg] = S[qg] * ca + So * cb2;
            M[qg] = Mn;
        }
    }
    if (l < 32) {
        int qg = g;
        size_t bn = bN + n0 + 16 * qg + c;
        size_t idx = ((size_t)chunk * (BB * NN) + bn) * 3;
        partP[idx + 0] = M[qg];
        partP[idx + 1] = F[qg];
        partP[idx + 2] = S[qg];
    }
}

// ---------------- stats stage B: merge chunks, compute alpha ----------------
__global__ __launch_bounds__(256) void stats_merge(const float* __restrict__ partP,
                                                   const float* __restrict__ valence,
                                                   float* __restrict__ rowstats) {
    size_t bn = (size_t)blockIdx.x * 256 + threadIdx.x;
    float M = -1e30f, F = 0.f, S = 0.f;
#pragma unroll
    for (int ch = 0; ch < MSPLIT; ++ch) {
        size_t idx = ((size_t)ch * (BB * NN) + bn) * 3;
        float m = partP[idx + 0], f = partP[idx + 1], s = partP[idx + 2];
        float Mn = fmaxf(M, m);
        float ca = __expf(M - Mn), cb2 = __expf(m - Mn);
        F = F * ca + f * cb2;
        S = S * ca + s * cb2;
        M = Mn;
    }
    float val = valence[bn];
    float scale = fminf(val / (1.0f + 1e-6f), 1.0f);
    float alpha = scale / (scale * S + 1e-8f * F);
    rowstats[bn * 2 + 0] = M;
    rowstats[bn * 2 + 1] = alpha;
}

// ---------------- PV: m-split chunks; 4 waves produce P tiles, consume own dc-quarter.
// use_split: block gx -> (bx, ch) covering m-tiles [32ch, min(32ch+32, bx+1)).
// bx<32 single-chunk blocks write Oh (f16, *alpha); others write fp32 partials.
__global__ __launch_bounds__(256) void pv16(const _Float16* __restrict__ Qb,
                                            const _Float16* __restrict__ Kb,
                                            const _Float16* __restrict__ Vt,
                                            const float* __restrict__ rowstats,
                                            _Float16* __restrict__ Oh,
                                            float* __restrict__ partO,
                                            int use_split) {
    __shared__ __align__(16) uint Plds[2][WV][2][16][20];
    int t = threadIdx.x;
    int w = t >> 6, l = t & 63, c = l & 15, g = l >> 4;
    int gx = blockIdx.x, b = blockIdx.y;
    int bx, ch;
    if (!use_split) {
        bx = (gx & 1) ? (NN / 32 - 1 - (gx >> 1)) : (gx >> 1);
        ch = 0;
    } else if (gx < 32)  { bx = gx; ch = 0; }
    else if (gx < 96)    { int r = gx - 32;  bx = 32 + (r >> 1); ch = r & 1; }
    else if (gx < 192)   { int r = gx - 96;  bx = 64 + r / 3;    ch = r % 3; }
    else                 { int r = gx - 192; bx = 96 + (r >> 2); ch = r & 3; }
    int t0 = use_split ? ch * 32 : 0;
    int t1 = use_split ? min(t0 + 32, bx + 1) : bx + 1;
    bool direct = (!use_split) || (bx < 32);

    size_t bN = (size_t)b * NN;
    int n0 = bx * 32;
    half8 qf[2][KC];
#pragma unroll
    for (int qg = 0; qg < 2; ++qg)
#pragma unroll
        for (int kc = 0; kc < KC; ++kc)
            qf[qg][kc] = *(const half8*)(Qb + (bN + n0 + 16 * qg + c) * FSP + kc * 32 + g * 8);
    int nq[2] = {n0 + c, n0 + 16 + c};
    float Mq[2], Aq[2];
#pragma unroll
    for (int qg = 0; qg < 2; ++qg) {
        Mq[qg] = rowstats[(bN + n0 + 16 * qg + c) * 2 + 0];
        Aq[qg] = rowstats[(bN + n0 + 16 * qg + c) * 2 + 1];
    }
    float4v acc[2][4];
#pragma unroll
    for (int qg = 0; qg < 2; ++qg)
#pragma unroll
        for (int d = 0; d < 4; ++d) acc[qg][d] = (float4v){0.f, 0.f, 0.f, 0.f};
    const _Float16* VtB = Vt + (size_t)b * DP * NN;

    int nt = t1 - t0;
    int rounds = (nt + WV - 1) / WV;
    for (int ro = 0; ro < rounds; ++ro) {
        int bufi = ro & 1;
        int tt = t0 + ro * WV + w;
        if (tt < t1) {
            int m0 = tt * 32;
            half8 kf[2][KC];
#pragma unroll
            for (int s = 0; s < 2; ++s)
#pragma unroll
                for (int kc = 0; kc < KC; ++kc)
                    kf[s][kc] = *(const half8*)(Kb + (bN + m0 + 16 * s + c) * FSP + kc * 32 + g * 8);
#pragma unroll
            for (int qg = 0; qg < 2; ++qg) {
#pragma unroll
                for (int s = 0; s < 2; ++s) {
                    float4v p = (float4v){0.f, 0.f, 0.f, 0.f};
#pragma unroll
                    for (int kc = 0; kc < KC; ++kc) p = MFMA16(kf[s][kc], qf[qg][kc], p, 0, 0, 0);
                    float wv[4];
#pragma unroll
                    for (int r = 0; r < 4; ++r) {
                        int m = m0 + 16 * s + 4 * g + r;
                        float sc = p[r] - 0.3f * fabsf((float)(nq[qg] - m));
                        wv[r] = (m <= nq[qg]) ? __expf(sc - Mq[qg]) : 0.f;
                    }
                    uint* dst = &Plds[bufi][w][qg][c][8 * s + 2 * g];
                    dst[0] = pack2(wv[0], wv[1]);
                    dst[1] = pack2(wv[2], wv[3]);
                }
            }
        }
        __syncthreads();
        int lim = (nt - ro * WV < WV) ? (nt - ro * WV) : WV;
        for (int ww = 0; ww < lim; ++ww) {
            int m0p = (t0 + ro * WV + ww) * 32;
            half8 pa0 = *(const half8*)&Plds[bufi][ww][0][c][4 * g];
            half8 pa1 = *(const half8*)&Plds[bufi][ww][1][c][4 * g];
#pragma unroll
            for (int dcl = 0; dcl < 4; ++dcl) {
                int dc = 4 * w + dcl;
                half8 vf = *(const half8*)(VtB + (size_t)(dc * 16 + c) * NN + m0p + g * 8);
                acc[0][dcl] = MFMA16(pa0, vf, acc[0][dcl], 0, 0, 0);
                acc[1][dcl] = MFMA16(pa1, vf, acc[1][dcl], 0, 0, 0);
            }
        }
    }
    if (direct) {
#pragma unroll
        for (int qg = 0; qg < 2; ++qg)
#pragma unroll
            for (int r = 0; r < 4; ++r) {
                float a = __shfl(Aq[qg], 4 * g + r);
                int nn = n0 + 16 * qg + 4 * g + r;
#pragma unroll
                for (int dcl = 0; dcl < 4; ++dcl)
                    Oh[(bN + nn) * DP + (4 * w + dcl) * 16 + c] = (_Float16)(a * acc[qg][dcl][r]);
            }
    } else {
#pragma unroll
        for (int qg = 0; qg < 2; ++qg)
#pragma unroll
            for (int r = 0; r < 4; ++r) {
                int nn = n0 + 16 * qg + 4 * g + r;
                size_t base = ((size_t)ch * (BB * NN) + bN + nn) * DP;
#pragma unroll
                for (int dcl = 0; dcl < 4; ++dcl)
                    partO[base + (4 * w + dcl) * 16 + c] = acc[qg][dcl][r];
            }
    }
}

// rows n >= 1024: Oh = alpha * sum_c partO[c]
__global__ __launch_bounds__(256) void pv_merge(const float* __restrict__ partO,
                                                const float* __restrict__ rowstats,
                                                _Float16* __restrict__ Oh) {
    int n = 1024 + blockIdx.x;
    int b = blockIdx.y;
    size_t bn = (size_t)b * NN + n;
    int d = threadIdx.x;
    int nc = (n >> 10) + 1;
    float s = 0.f;
    for (int cc = 0; cc < nc; ++cc)
        s += partO[((size_t)cc * (BB * NN) + bn) * DP + d];
    float alpha = rowstats[bn * 2 + 1];
    Oh[bn * DP + d] = (_Float16)(alpha * s);
}

// ---------------- launch ----------------
extern "C" void kernel_launch(void* const* d_in, const int* in_sizes, int n_in,
                              void* d_out, int out_size, void* d_ws, size_t ws_size,
                              hipStream_t stream) {
    (void)in_sizes; (void)n_in; (void)out_size;
    const float* charge  = (const float*)d_in[0];
    const float* shell   = (const float*)d_in[1];
    const float* mass    = (const float*)d_in[2];
    const float* valence = (const float*)d_in[3];
    const float* x  = (const float*)d_in[5];
    const float* Wv = (const float*)d_in[6];
    const float* bv = (const float*)d_in[7];
    const float* Wo = (const float*)d_in[8];
    const float* bo = (const float*)d_in[9];
    float* out = (float*)d_out;

    const size_t BN = (size_t)BB * NN;
    char* w = (char*)d_ws;
    _Float16* Qb  = (_Float16*)w;              w += BN * FSP * 2;
    _Float16* Kb  = (_Float16*)w;              w += BN * FSP * 2;
    _Float16* xh  = (_Float16*)w;              w += BN * DP * 2;
    _Float16* Vh  = (_Float16*)w;              w += BN * DP * 2;
    _Float16* Vt  = (_Float16*)w;              w += BN * DP * 2;
    _Float16* Wvh = (_Float16*)w;              w += DP * DP * 2;
    _Float16* Woh = (_Float16*)w;              w += DP * DP * 2;
    float* rowstats = (float*)w;               w += BN * 2 * 4;
    float* partP    = (float*)w;               w += (size_t)MSPLIT * BN * 3 * 4;
    float* partO    = (float*)w;               w += (size_t)4 * BN * DP * 4;  // 67 MB
    _Float16* Oh = xh;  // xh dead after V-GEMM

    size_t need = (size_t)(w - (char*)d_ws);
    int use_split = (ws_size >= need) ? 1 : 0;

    prep_x<<<BB * NN, 256, 0, stream>>>(x, xh);
    prep_w<<<dim3(DP, 2), 256, 0, stream>>>(Wv, Wo, Wvh, Woh);
    prep_feat<<<BB * NN, 64, 0, stream>>>(charge, shell, mass, Qb, Kb);
    gemm16<true><<<dim3(BB * NN / 32, DP / 32), 64, 0, stream>>>(xh, Wvh, bv, (void*)Vh);
    transpose_v<<<dim3(NN / 64, DP / 64, BB), 256, 0, stream>>>(Vh, Vt);
    stats_partial<<<dim3(NN / 32, MSPLIT, BB), 64, 0, stream>>>(Qb, Kb, partP);
    stats_merge<<<BN / 256, 256, 0, stream>>>(partP, valence, rowstats);
    pv16<<<dim3(use_split ? 320 : 128, BB), 256, 0, stream>>>(Qb, Kb, Vt, rowstats, Oh,
                                                              partO, use_split);
    if (use_split)
        pv_merge<<<dim3(NN - 1024, BB), 256, 0, stream>>>(partO, rowstats, Oh);
    gemm16<false><<<dim3(BB * NN / 32, DP / 32), 64, 0, stream>>>(Oh, Woh, bo, (void*)out);
}